// Round 1
// baseline (305.598 us; speedup 1.0000x reference)
//
#include <hip/hip_runtime.h>
#include <cstdint>
#include <cstddef>

#define H_IN   1024
#define H_OUTD 1024
#define PDIM   512
#define BSZ    16
#define LSEQ   1024
#define BLM    (BSZ * LSEQ)   // 16384 rows

typedef __bf16 bf16_t;
typedef __bf16 bf16x8 __attribute__((ext_vector_type(8)));
typedef float  floatx4 __attribute__((ext_vector_type(4)));

// exact RNE fp32 -> bf16 bit conversion
__device__ __forceinline__ unsigned short f2bf(float f) {
    unsigned u = __float_as_uint(f);
    u = u + 0x7fffu + ((u >> 16) & 1u);
    return (unsigned short)(u >> 16);
}

__device__ __forceinline__ void gl_lds16(const void* g, void* l) {
    __builtin_amdgcn_global_load_lds(
        (const __attribute__((address_space(1))) void*)g,
        (__attribute__((address_space(3))) void*)l, 16, 0, 0);
}

// ---------------- per-p constants: step = exp(log_step), Lam = -(softplus(raw)+1e-3)
__global__ void consts_kernel(const float* __restrict__ Lraw,
                              const float* __restrict__ lstep,
                              float* __restrict__ stepv,
                              float* __restrict__ lamv) {
    int p = blockIdx.x * blockDim.x + threadIdx.x;
    if (p < PDIM) {
        stepv[p] = expf(lstep[p]);  // STEP_RESCALE = 1.0
        float x = Lraw[p];
        // jax.nn.softplus(x) = max(x,0) + log1p(exp(-|x|))
        float sp = fmaxf(x, 0.0f) + log1pf(expf(-fabsf(x)));
        lamv[p] = -(sp + 1e-3f);
    }
}

// ---------------- fp32 -> bf16 cast, 4 elements/thread
__global__ void cvt_kernel(const float4* __restrict__ src,
                           ushort4* __restrict__ dst, int n4) {
    int i = blockIdx.x * blockDim.x + threadIdx.x;
    if (i < n4) {
        float4 v = src[i];
        ushort4 o;
        o.x = f2bf(v.x); o.y = f2bf(v.y); o.z = f2bf(v.z); o.w = f2bf(v.w);
        dst[i] = o;
    }
}

// ---------------- NT bf16 MFMA GEMM: out[m,n] = sum_k A[m,k]*Bm[n,k]  (+ D[n]*U[m,n] if EPI)
// 128x128 tile, BK=32, 256 threads (4 waves, each 64x64), 16x16x32 MFMA.
// LDS staged via global_load_lds width=16 with XOR swizzle (slot = seg ^ (row&3))
// so ds_read_b128 fragment reads are ~conflict-free.
template<int EPI>
__global__ __launch_bounds__(256, 2)
void gemm_nt(const bf16_t* __restrict__ A, const bf16_t* __restrict__ Bm,
             float* __restrict__ C, int M, int N, int K,
             const float* __restrict__ Dv, const float* __restrict__ U) {
    __shared__ bf16_t As[128 * 32];
    __shared__ bf16_t Bs[128 * 32];

    const int tid  = threadIdx.x;
    const int lane = tid & 63;
    const int w    = tid >> 6;
    const int m0   = blockIdx.y << 7;
    const int n0   = blockIdx.x << 7;
    const int wm   = (w & 1) << 6;
    const int wn   = (w >> 1) << 6;
    const int r16  = lane & 15;
    const int q    = lane >> 4;
    const int fsw  = (q ^ (r16 & 3)) << 3;   // fragment slot offset (elements)

    // staging: each wave covers 32 rows of each tile via two 16-row chunks
    const int srow = lane >> 2;              // 0..15 within chunk
    const int seg  = (lane & 3) ^ (srow & 3);
    const int c0   = w * 32;
    const int c1   = c0 + 16;

    const bf16_t* gA0 = A  + (size_t)(m0 + c0 + srow) * K + seg * 8;
    const bf16_t* gA1 = A  + (size_t)(m0 + c1 + srow) * K + seg * 8;
    const bf16_t* gB0 = Bm + (size_t)(n0 + c0 + srow) * K + seg * 8;
    const bf16_t* gB1 = Bm + (size_t)(n0 + c1 + srow) * K + seg * 8;
    bf16_t* lA0 = &As[c0 * 32];
    bf16_t* lA1 = &As[c1 * 32];
    bf16_t* lB0 = &Bs[c0 * 32];
    bf16_t* lB1 = &Bs[c1 * 32];

    floatx4 acc[4][4] = {};

    for (int k0 = 0; k0 < K; k0 += 32) {
        gl_lds16(gA0 + k0, lA0);
        gl_lds16(gA1 + k0, lA1);
        gl_lds16(gB0 + k0, lB0);
        gl_lds16(gB1 + k0, lB1);
        __syncthreads();   // drains vmcnt: LDS tiles ready

        bf16x8 af[4], bfr[4];
#pragma unroll
        for (int i = 0; i < 4; ++i) {
            af[i]  = *(const bf16x8*)&As[(wm + i * 16 + r16) * 32 + fsw];
            bfr[i] = *(const bf16x8*)&Bs[(wn + i * 16 + r16) * 32 + fsw];
        }
#pragma unroll
        for (int mi = 0; mi < 4; ++mi)
#pragma unroll
            for (int ni = 0; ni < 4; ++ni)
                acc[mi][ni] = __builtin_amdgcn_mfma_f32_16x16x32_bf16(
                    af[mi], bfr[ni], acc[mi][ni], 0, 0, 0);
        __syncthreads();   // all waves done reading before next overwrite
    }

    // epilogue: D row = q*4 + e, col = r16 (verified C/D layout)
#pragma unroll
    for (int mi = 0; mi < 4; ++mi) {
#pragma unroll
        for (int e = 0; e < 4; ++e) {
            const int m = m0 + wm + mi * 16 + q * 4 + e;
#pragma unroll
            for (int ni = 0; ni < 4; ++ni) {
                const int n = n0 + wn + ni * 16 + r16;
                const size_t idx = (size_t)m * N + n;
                float v = acc[mi][ni][e];
                if (EPI == 1) v += Dv[n] * U[idx];
                C[idx] = v;
            }
        }
    }
}

// ---------------- sequential scan over L per (b,p); mirrors reference exactly:
// A_bar = exp(min(Lam*Delta,20)); A_cum = cumprod; gamma = |Lam|>1e-6 ? (A_bar-1)/Lam : Delta
// z = gamma*Bu/(A_cum+1e-9); s = cumsum z; x = A_cum*s  -> stored bf16 for GEMM2
__global__ __launch_bounds__(256)
void scan_kernel(const float* __restrict__ Bu, const float* __restrict__ ts,
                 const float* __restrict__ stepv, const float* __restrict__ lamv,
                 unsigned short* __restrict__ Xbf) {
    const int blk = blockIdx.x;
    const int b   = blk >> 1;
    const int p   = ((blk & 1) << 8) + threadIdx.x;

    const float lam = lamv[p];
    const float stp = stepv[p];
    const float rlam = 1.0f / lam;
    const bool  lam_big = fabsf(lam) > 1e-6f;

    float acum = 1.0f, s = 0.0f;
    const float* bu = Bu + ((size_t)b * LSEQ) * PDIM + p;
    const float* tb = ts + b * LSEQ;
    unsigned short* xo = Xbf + ((size_t)b * LSEQ) * PDIM + p;

#pragma unroll 4
    for (int l = 0; l < LSEQ; ++l) {
        float t     = tb[l];
        float delta = fmaxf(stp * t, 0.0f);
        float e     = fminf(lam * delta, 20.0f);
        float abar  = __expf(e);
        float gamma = lam_big ? (abar - 1.0f) * rlam : delta;
        acum *= abar;                       // inclusive cumprod
        float bv = bu[(size_t)l * PDIM];
        float z  = gamma * bv * __builtin_amdgcn_rcpf(acum + 1e-9f);
        s += z;                             // inclusive cumsum
        float x = acum * s;
        xo[(size_t)l * PDIM] = f2bf(x);
    }
}

extern "C" void kernel_launch(void* const* d_in, const int* in_sizes, int n_in,
                              void* d_out, int out_size, void* d_ws, size_t ws_size,
                              hipStream_t stream) {
    (void)in_sizes; (void)n_in; (void)out_size; (void)ws_size;
    const float* u  = (const float*)d_in[0];
    const float* ts = (const float*)d_in[1];
    const float* Lr = (const float*)d_in[2];
    const float* ls = (const float*)d_in[3];
    const float* Bm = (const float*)d_in[4];
    const float* Cm = (const float*)d_in[5];
    const float* Dv = (const float*)d_in[6];
    float* out = (float*)d_out;

    char* ws = (char*)d_ws;
    bf16_t* u_bf  = (bf16_t*)(ws);                                   // 32 MB
    bf16_t* B_bf  = (bf16_t*)(ws + 33554432);                        // 1 MB
    bf16_t* C_bf  = (bf16_t*)(ws + 33554432 + 1048576);              // 1 MB
    float*  Bu    = (float*) (ws + 33554432 + 2097152);              // 32 MB
    bf16_t* X_bf  = (bf16_t*)(ws + 33554432 + 2097152 + 33554432);   // 16 MB
    float*  stepv = (float*) (ws + 33554432 + 2097152 + 33554432 + 16777216);
    float*  lamv  = stepv + PDIM;

    consts_kernel<<<1, 512, 0, stream>>>(Lr, ls, stepv, lamv);

    cvt_kernel<<<BLM * H_IN / 4 / 256, 256, 0, stream>>>(
        (const float4*)u, (ushort4*)u_bf, BLM * H_IN / 4);
    cvt_kernel<<<PDIM * H_IN / 4 / 256, 256, 0, stream>>>(
        (const float4*)Bm, (ushort4*)B_bf, PDIM * H_IN / 4);
    cvt_kernel<<<H_OUTD * PDIM / 4 / 256, 256, 0, stream>>>(
        (const float4*)Cm, (ushort4*)C_bf, H_OUTD * PDIM / 4);

    // GEMM1: Bu[16384,512] = u_bf[16384,1024] . B_bf[512,1024]^T
    gemm_nt<0><<<dim3(PDIM / 128, BLM / 128), 256, 0, stream>>>(
        u_bf, B_bf, Bu, BLM, PDIM, H_IN, nullptr, nullptr);

    // scan -> x (bf16)
    scan_kernel<<<32, 256, 0, stream>>>(Bu, ts, stepv, lamv,
                                        (unsigned short*)X_bf);

    // GEMM2: out[16384,1024] = X_bf[16384,512] . C_bf[1024,512]^T + D*u
    gemm_nt<1><<<dim3(H_OUTD / 128, BLM / 128), 256, 0, stream>>>(
        X_bf, C_bf, out, BLM, H_OUTD, PDIM, Dv, u);
}

// Round 2
// 217.250 us; speedup vs baseline: 1.4067x; 1.4067x over previous
//
#include <hip/hip_runtime.h>
#include <cstdint>
#include <cstddef>

#define H_IN   1024
#define H_OUTD 1024
#define PDIM   512
#define BSZ    16
#define LSEQ   1024
#define BLM    (BSZ * LSEQ)   // 16384 rows
#define CCH    32             // chunks along L
#define CLEN   32             // steps per chunk (CCH*CLEN == LSEQ)

typedef __bf16 bf16_t;
typedef __bf16 bf16x8 __attribute__((ext_vector_type(8)));
typedef float  floatx4 __attribute__((ext_vector_type(4)));

// exact RNE fp32 -> bf16 bit conversion
__device__ __forceinline__ unsigned short f2bf(float f) {
    unsigned u = __float_as_uint(f);
    u = u + 0x7fffu + ((u >> 16) & 1u);
    return (unsigned short)(u >> 16);
}

__device__ __forceinline__ void gl_lds16(const void* g, void* l) {
    __builtin_amdgcn_global_load_lds(
        (const __attribute__((address_space(1))) void*)g,
        (__attribute__((address_space(3))) void*)l, 16, 0, 0);
}

// ---------------- per-p constants: step = exp(log_step), Lam = -(softplus(raw)+1e-3)
__global__ void consts_kernel(const float* __restrict__ Lraw,
                              const float* __restrict__ lstep,
                              float* __restrict__ stepv,
                              float* __restrict__ lamv) {
    int p = blockIdx.x * blockDim.x + threadIdx.x;
    if (p < PDIM) {
        stepv[p] = expf(lstep[p]);  // STEP_RESCALE = 1.0
        float x = Lraw[p];
        // jax.nn.softplus(x) = max(x,0) + log1p(exp(-|x|))
        float sp = fmaxf(x, 0.0f) + log1pf(expf(-fabsf(x)));
        lamv[p] = -(sp + 1e-3f);
    }
}

// ---------------- fp32 -> bf16 cast, 4 elements/thread
__global__ void cvt_kernel(const float4* __restrict__ src,
                           ushort4* __restrict__ dst, int n4) {
    int i = blockIdx.x * blockDim.x + threadIdx.x;
    if (i < n4) {
        float4 v = src[i];
        ushort4 o;
        o.x = f2bf(v.x); o.y = f2bf(v.y); o.z = f2bf(v.z); o.w = f2bf(v.w);
        dst[i] = o;
    }
}

// ---------------- NT bf16 MFMA GEMM: out[m,n] = sum_k A[m,k]*Bm[n,k]  (+ D[n]*U[m,n] if EPI)
// 128x128 tile, BK=32, 256 threads (4 waves, each 64x64), 16x16x32 MFMA.
template<int EPI>
__global__ __launch_bounds__(256, 2)
void gemm_nt(const bf16_t* __restrict__ A, const bf16_t* __restrict__ Bm,
             float* __restrict__ C, int M, int N, int K,
             const float* __restrict__ Dv, const float* __restrict__ U) {
    __shared__ bf16_t As[128 * 32];
    __shared__ bf16_t Bs[128 * 32];

    const int tid  = threadIdx.x;
    const int lane = tid & 63;
    const int w    = tid >> 6;
    const int m0   = blockIdx.y << 7;
    const int n0   = blockIdx.x << 7;
    const int wm   = (w & 1) << 6;
    const int wn   = (w >> 1) << 6;
    const int r16  = lane & 15;
    const int q    = lane >> 4;
    const int fsw  = (q ^ (r16 & 3)) << 3;   // fragment slot offset (elements)

    // staging: each wave covers 32 rows of each tile via two 16-row chunks
    const int srow = lane >> 2;              // 0..15 within chunk
    const int seg  = (lane & 3) ^ (srow & 3);
    const int c0   = w * 32;
    const int c1   = c0 + 16;

    const bf16_t* gA0 = A  + (size_t)(m0 + c0 + srow) * K + seg * 8;
    const bf16_t* gA1 = A  + (size_t)(m0 + c1 + srow) * K + seg * 8;
    const bf16_t* gB0 = Bm + (size_t)(n0 + c0 + srow) * K + seg * 8;
    const bf16_t* gB1 = Bm + (size_t)(n0 + c1 + srow) * K + seg * 8;
    bf16_t* lA0 = &As[c0 * 32];
    bf16_t* lA1 = &As[c1 * 32];
    bf16_t* lB0 = &Bs[c0 * 32];
    bf16_t* lB1 = &Bs[c1 * 32];

    floatx4 acc[4][4] = {};

    for (int k0 = 0; k0 < K; k0 += 32) {
        gl_lds16(gA0 + k0, lA0);
        gl_lds16(gA1 + k0, lA1);
        gl_lds16(gB0 + k0, lB0);
        gl_lds16(gB1 + k0, lB1);
        __syncthreads();   // drains vmcnt: LDS tiles ready

        bf16x8 af[4], bfr[4];
#pragma unroll
        for (int i = 0; i < 4; ++i) {
            af[i]  = *(const bf16x8*)&As[(wm + i * 16 + r16) * 32 + fsw];
            bfr[i] = *(const bf16x8*)&Bs[(wn + i * 16 + r16) * 32 + fsw];
        }
#pragma unroll
        for (int mi = 0; mi < 4; ++mi)
#pragma unroll
            for (int ni = 0; ni < 4; ++ni)
                acc[mi][ni] = __builtin_amdgcn_mfma_f32_16x16x32_bf16(
                    af[mi], bfr[ni], acc[mi][ni], 0, 0, 0);
        __syncthreads();   // all waves done reading before next overwrite
    }

    // epilogue: D row = q*4 + e, col = r16 (verified C/D layout)
#pragma unroll
    for (int mi = 0; mi < 4; ++mi) {
#pragma unroll
        for (int e = 0; e < 4; ++e) {
            const int m = m0 + wm + mi * 16 + q * 4 + e;
#pragma unroll
            for (int ni = 0; ni < 4; ++ni) {
                const int n = n0 + wn + ni * 16 + r16;
                const size_t idx = (size_t)m * N + n;
                float v = acc[mi][ni][e];
                if (EPI == 1) v += Dv[n] * U[idx];
                C[idx] = v;
            }
        }
    }
}

// ---------------- chunked parallel scan, 3 phases.
// Recurrence (algebraically == reference cumprod/cumsum form):
//   x_l = abar_l * x_{l-1} + gamma_l * bu_l
// Phase 1: per (b, chunk, p): P = prod(abar), S = chunk-local x from 0.
__global__ __launch_bounds__(512)
void scan_part1(const float* __restrict__ Bu, const float* __restrict__ ts,
                const float* __restrict__ stepv, const float* __restrict__ lamv,
                float* __restrict__ Pagg, float* __restrict__ Sagg) {
    const int c = blockIdx.x;
    const int b = blockIdx.y;
    const int p = threadIdx.x;

    const float lam  = lamv[p];
    const float stp  = stepv[p];
    const float rlam = 1.0f / lam;
    const bool  lam_big = fabsf(lam) > 1e-6f;

    const float* bu = Bu + ((size_t)b * LSEQ + c * CLEN) * PDIM + p;
    const float* tb = ts + b * LSEQ + c * CLEN;

    float P = 1.0f, S = 0.0f;
#pragma unroll 8
    for (int i = 0; i < CLEN; ++i) {
        float t     = tb[i];
        float delta = fmaxf(stp * t, 0.0f);
        float e     = fminf(lam * delta, 20.0f);
        float abar  = __expf(e);
        float gamma = lam_big ? (abar - 1.0f) * rlam : delta;
        S = fmaf(abar, S, gamma * bu[(size_t)i * PDIM]);
        P *= abar;
    }
    const size_t o = ((size_t)b * CCH + c) * PDIM + p;
    Pagg[o] = P;
    Sagg[o] = S;
}

// Phase 2: per (b,p), scan over CCH chunk aggregates -> entering state X0 per chunk.
__global__ __launch_bounds__(256)
void scan_chunk(const float* __restrict__ Pagg, const float* __restrict__ Sagg,
                float* __restrict__ X0) {
    const int gid = blockIdx.x * 256 + threadIdx.x;   // 0..8191
    const int b   = gid >> 9;
    const int p   = gid & 511;

    float x = 0.0f;
#pragma unroll 8
    for (int c = 0; c < CCH; ++c) {
        const size_t o = ((size_t)b * CCH + c) * PDIM + p;
        X0[o] = x;                       // state ENTERING chunk c
        x = fmaf(Pagg[o], x, Sagg[o]);
    }
}

// Phase 3: re-walk each chunk from its entering state, emit x as bf16.
__global__ __launch_bounds__(512)
void scan_part3(const float* __restrict__ Bu, const float* __restrict__ ts,
                const float* __restrict__ stepv, const float* __restrict__ lamv,
                const float* __restrict__ X0, unsigned short* __restrict__ Xbf) {
    const int c = blockIdx.x;
    const int b = blockIdx.y;
    const int p = threadIdx.x;

    const float lam  = lamv[p];
    const float stp  = stepv[p];
    const float rlam = 1.0f / lam;
    const bool  lam_big = fabsf(lam) > 1e-6f;

    const float* bu = Bu + ((size_t)b * LSEQ + c * CLEN) * PDIM + p;
    const float* tb = ts + b * LSEQ + c * CLEN;
    unsigned short* xo = Xbf + ((size_t)b * LSEQ + c * CLEN) * PDIM + p;

    float x = X0[((size_t)b * CCH + c) * PDIM + p];
#pragma unroll 8
    for (int i = 0; i < CLEN; ++i) {
        float t     = tb[i];
        float delta = fmaxf(stp * t, 0.0f);
        float e     = fminf(lam * delta, 20.0f);
        float abar  = __expf(e);
        float gamma = lam_big ? (abar - 1.0f) * rlam : delta;
        x = fmaf(abar, x, gamma * bu[(size_t)i * PDIM]);
        xo[(size_t)i * PDIM] = f2bf(x);
    }
}

extern "C" void kernel_launch(void* const* d_in, const int* in_sizes, int n_in,
                              void* d_out, int out_size, void* d_ws, size_t ws_size,
                              hipStream_t stream) {
    (void)in_sizes; (void)n_in; (void)out_size; (void)ws_size;
    const float* u  = (const float*)d_in[0];
    const float* ts = (const float*)d_in[1];
    const float* Lr = (const float*)d_in[2];
    const float* ls = (const float*)d_in[3];
    const float* Bm = (const float*)d_in[4];
    const float* Cm = (const float*)d_in[5];
    const float* Dv = (const float*)d_in[6];
    float* out = (float*)d_out;

    char* ws = (char*)d_ws;
    bf16_t* u_bf  = (bf16_t*)(ws);                                   // 32 MB
    bf16_t* B_bf  = (bf16_t*)(ws + 33554432);                        // 1 MB
    bf16_t* C_bf  = (bf16_t*)(ws + 33554432 + 1048576);              // 1 MB
    float*  Bu    = (float*) (ws + 33554432 + 2097152);              // 32 MB
    bf16_t* X_bf  = (bf16_t*)(ws + 33554432 + 2097152 + 33554432);   // 16 MB
    float*  stepv = (float*) (ws + 33554432 + 2097152 + 33554432 + 16777216);
    float*  lamv  = stepv + PDIM;
    // scan aggregates alias u_bf (dead after gemm1; stream-ordered): 3 MB
    float*  Pagg  = (float*)(ws);
    float*  Sagg  = (float*)(ws + 1048576);
    float*  X0    = (float*)(ws + 2097152);

    consts_kernel<<<1, 512, 0, stream>>>(Lr, ls, stepv, lamv);

    cvt_kernel<<<BLM * H_IN / 4 / 256, 256, 0, stream>>>(
        (const float4*)u, (ushort4*)u_bf, BLM * H_IN / 4);
    cvt_kernel<<<PDIM * H_IN / 4 / 256, 256, 0, stream>>>(
        (const float4*)Bm, (ushort4*)B_bf, PDIM * H_IN / 4);
    cvt_kernel<<<H_OUTD * PDIM / 4 / 256, 256, 0, stream>>>(
        (const float4*)Cm, (ushort4*)C_bf, H_OUTD * PDIM / 4);

    // GEMM1: Bu[16384,512] = u_bf[16384,1024] . B_bf[512,1024]^T
    gemm_nt<0><<<dim3(PDIM / 128, BLM / 128), 256, 0, stream>>>(
        u_bf, B_bf, Bu, BLM, PDIM, H_IN, nullptr, nullptr);

    // chunked scan -> X (bf16)
    scan_part1<<<dim3(CCH, BSZ), 512, 0, stream>>>(Bu, ts, stepv, lamv, Pagg, Sagg);
    scan_chunk<<<BSZ * PDIM / 256, 256, 0, stream>>>(Pagg, Sagg, X0);
    scan_part3<<<dim3(CCH, BSZ), 512, 0, stream>>>(Bu, ts, stepv, lamv, X0,
                                                   (unsigned short*)X_bf);

    // GEMM2: out[16384,1024] = X_bf[16384,512] . C_bf[1024,512]^T + D*u
    gemm_nt<1><<<dim3(H_OUTD / 128, BLM / 128), 256, 0, stream>>>(
        X_bf, C_bf, out, BLM, H_OUTD, PDIM, Dv, u);
}

// Round 4
// 204.119 us; speedup vs baseline: 1.4972x; 1.0643x over previous
//
#include <hip/hip_runtime.h>
#include <cstdint>
#include <cstddef>

#define H_IN   1024
#define H_OUTD 1024
#define PDIM   512
#define BSZ    16
#define LSEQ   1024
#define BLM    (BSZ * LSEQ)   // 16384 rows
#define CCH    32             // chunks along L
#define CLEN   32             // steps per chunk (CCH*CLEN == LSEQ)

typedef __bf16 bf16_t;
typedef __bf16 bf16x8 __attribute__((ext_vector_type(8)));
typedef float  floatx4 __attribute__((ext_vector_type(4)));

// exact RNE fp32 -> bf16 bit conversion
__device__ __forceinline__ unsigned short f2bf(float f) {
    unsigned u = __float_as_uint(f);
    u = u + 0x7fffu + ((u >> 16) & 1u);
    return (unsigned short)(u >> 16);
}
__device__ __forceinline__ float bf2f(unsigned short s) {
    return __uint_as_float((unsigned)s << 16);
}

__device__ __forceinline__ void gl_lds16(const void* g, void* l) {
    __builtin_amdgcn_global_load_lds(
        (const __attribute__((address_space(1))) void*)g,
        (__attribute__((address_space(3))) void*)l, 16, 0, 0);
}

// ---------------- fused setup: per-p constants + B/C fp32->bf16 casts
// grid = 1024 blocks x 256 (131072 float4 for B, 131072 for C)
__global__ void setup_kernel(const float* __restrict__ Lraw,
                             const float* __restrict__ lstep,
                             float* __restrict__ stepv,
                             float* __restrict__ lamv,
                             const float4* __restrict__ Bsrc,
                             ushort4* __restrict__ Bdst,
                             const float4* __restrict__ Csrc,
                             ushort4* __restrict__ Cdst) {
    const int gid = blockIdx.x * 256 + threadIdx.x;
    if (gid < PDIM) {
        stepv[gid] = expf(lstep[gid]);  // STEP_RESCALE = 1.0
        float x = Lraw[gid];
        // jax.nn.softplus(x) = max(x,0) + log1p(exp(-|x|))
        float sp = fmaxf(x, 0.0f) + log1pf(expf(-fabsf(x)));
        lamv[gid] = -(sp + 1e-3f);
    }
    const int nB = PDIM * H_IN / 4;   // 131072
    if (gid < nB) {
        float4 v = Bsrc[gid];
        ushort4 o;
        o.x = f2bf(v.x); o.y = f2bf(v.y); o.z = f2bf(v.z); o.w = f2bf(v.w);
        Bdst[gid] = o;
    } else {
        const int g2 = gid - nB;      // < 131072
        float4 v = Csrc[g2];
        ushort4 o;
        o.x = f2bf(v.x); o.y = f2bf(v.y); o.z = f2bf(v.z); o.w = f2bf(v.w);
        Cdst[g2] = o;
    }
}

// ---------------- fp32 -> bf16 cast (u), 4 elements/thread
__global__ void cvt_kernel(const float4* __restrict__ src,
                           ushort4* __restrict__ dst, int n4) {
    int i = blockIdx.x * blockDim.x + threadIdx.x;
    if (i < n4) {
        float4 v = src[i];
        ushort4 o;
        o.x = f2bf(v.x); o.y = f2bf(v.y); o.z = f2bf(v.z); o.w = f2bf(v.w);
        dst[i] = o;
    }
}

// ---------------- NT bf16 MFMA GEMM: out[m,n] = sum_k A[m,k]*Bm[n,k]
// EPI==1: += Dv[n]*bf2f(U[m,n]).  OUTBF==1: store bf16 to Cb, else fp32 to Cf.
// 128x128 tile, BK=32, 256 threads (4 waves, each 64x64), 16x16x32 MFMA.
template<int EPI, int OUTBF>
__global__ __launch_bounds__(256, 4)
void gemm_nt(const bf16_t* __restrict__ A, const bf16_t* __restrict__ Bm,
             float* __restrict__ Cf, unsigned short* __restrict__ Cb,
             int M, int N, int K,
             const float* __restrict__ Dv, const unsigned short* __restrict__ U) {
    __shared__ bf16_t As[128 * 32];
    __shared__ bf16_t Bs[128 * 32];

    const int tid  = threadIdx.x;
    const int lane = tid & 63;
    const int w    = tid >> 6;
    const int m0   = blockIdx.y << 7;
    const int n0   = blockIdx.x << 7;
    const int wm   = (w & 1) << 6;
    const int wn   = (w >> 1) << 6;
    const int r16  = lane & 15;
    const int q    = lane >> 4;
    const int fsw  = (q ^ (r16 & 3)) << 3;   // XOR-swizzled fragment slot

    // staging: each wave covers 32 rows of each tile via two 16-row chunks
    const int srow = lane >> 2;              // 0..15 within chunk
    const int seg  = (lane & 3) ^ (srow & 3);
    const int c0   = w * 32;
    const int c1   = c0 + 16;

    const bf16_t* gA0 = A  + (size_t)(m0 + c0 + srow) * K + seg * 8;
    const bf16_t* gA1 = A  + (size_t)(m0 + c1 + srow) * K + seg * 8;
    const bf16_t* gB0 = Bm + (size_t)(n0 + c0 + srow) * K + seg * 8;
    const bf16_t* gB1 = Bm + (size_t)(n0 + c1 + srow) * K + seg * 8;
    bf16_t* lA0 = &As[c0 * 32];
    bf16_t* lA1 = &As[c1 * 32];
    bf16_t* lB0 = &Bs[c0 * 32];
    bf16_t* lB1 = &Bs[c1 * 32];

    floatx4 acc[4][4] = {};

    for (int k0 = 0; k0 < K; k0 += 32) {
        gl_lds16(gA0 + k0, lA0);
        gl_lds16(gA1 + k0, lA1);
        gl_lds16(gB0 + k0, lB0);
        gl_lds16(gB1 + k0, lB1);
        __syncthreads();   // drains vmcnt: LDS tiles ready

        bf16x8 af[4], bfr[4];
#pragma unroll
        for (int i = 0; i < 4; ++i) {
            af[i]  = *(const bf16x8*)&As[(wm + i * 16 + r16) * 32 + fsw];
            bfr[i] = *(const bf16x8*)&Bs[(wn + i * 16 + r16) * 32 + fsw];
        }
#pragma unroll
        for (int mi = 0; mi < 4; ++mi)
#pragma unroll
            for (int ni = 0; ni < 4; ++ni)
                acc[mi][ni] = __builtin_amdgcn_mfma_f32_16x16x32_bf16(
                    af[mi], bfr[ni], acc[mi][ni], 0, 0, 0);
        __syncthreads();   // all waves done reading before next overwrite
    }

    // epilogue: C/D layout row = q*4 + e, col = r16 (verified)
    float dn[4];
    if (EPI == 1) {
#pragma unroll
        for (int ni = 0; ni < 4; ++ni) dn[ni] = Dv[n0 + wn + ni * 16 + r16];
    }
#pragma unroll
    for (int mi = 0; mi < 4; ++mi) {
#pragma unroll
        for (int e = 0; e < 4; ++e) {
            const int m = m0 + wm + mi * 16 + q * 4 + e;
#pragma unroll
            for (int ni = 0; ni < 4; ++ni) {
                const int n = n0 + wn + ni * 16 + r16;
                const size_t idx = (size_t)m * N + n;
                float v = acc[mi][ni][e];
                if (EPI == 1) v += dn[ni] * bf2f(U[idx]);
                if (OUTBF == 1) Cb[idx] = f2bf(v);
                else            Cf[idx] = v;
            }
        }
    }
}

// ---------------- chunked parallel scan, 3 phases.
// Recurrence (algebraically == reference cumprod/cumsum form):
//   x_l = abar_l * x_{l-1} + gamma_l * bu_l
// Phase 1: per (b, chunk, p): P = prod(abar), S = chunk-local x from 0.
__global__ __launch_bounds__(512)
void scan_part1(const unsigned short* __restrict__ Bu, const float* __restrict__ ts,
                const float* __restrict__ stepv, const float* __restrict__ lamv,
                float* __restrict__ Pagg, float* __restrict__ Sagg) {
    const int c = blockIdx.x;
    const int b = blockIdx.y;
    const int p = threadIdx.x;

    const float lam  = lamv[p];
    const float stp  = stepv[p];
    const float rlam = 1.0f / lam;
    const bool  lam_big = fabsf(lam) > 1e-6f;

    const unsigned short* bu = Bu + ((size_t)b * LSEQ + c * CLEN) * PDIM + p;
    const float* tb = ts + b * LSEQ + c * CLEN;

    float P = 1.0f, S = 0.0f;
#pragma unroll 8
    for (int i = 0; i < CLEN; ++i) {
        float t     = tb[i];
        float delta = fmaxf(stp * t, 0.0f);
        float e     = fminf(lam * delta, 20.0f);
        float abar  = __expf(e);
        float gamma = lam_big ? (abar - 1.0f) * rlam : delta;
        S = fmaf(abar, S, gamma * bf2f(bu[(size_t)i * PDIM]));
        P *= abar;
    }
    const size_t o = ((size_t)b * CCH + c) * PDIM + p;
    Pagg[o] = P;
    Sagg[o] = S;
}

// Phase 2: per (b,p), scan over CCH chunk aggregates -> entering state X0 per chunk.
__global__ __launch_bounds__(256)
void scan_chunk(const float* __restrict__ Pagg, const float* __restrict__ Sagg,
                float* __restrict__ X0) {
    const int gid = blockIdx.x * 256 + threadIdx.x;   // 0..8191
    const int b   = gid >> 9;
    const int p   = gid & 511;

    float x = 0.0f;
#pragma unroll 8
    for (int c = 0; c < CCH; ++c) {
        const size_t o = ((size_t)b * CCH + c) * PDIM + p;
        X0[o] = x;                       // state ENTERING chunk c
        x = fmaf(Pagg[o], x, Sagg[o]);
    }
}

// Phase 3: re-walk each chunk from its entering state, emit x as bf16.
__global__ __launch_bounds__(512)
void scan_part3(const unsigned short* __restrict__ Bu, const float* __restrict__ ts,
                const float* __restrict__ stepv, const float* __restrict__ lamv,
                const float* __restrict__ X0, unsigned short* __restrict__ Xbf) {
    const int c = blockIdx.x;
    const int b = blockIdx.y;
    const int p = threadIdx.x;

    const float lam  = lamv[p];
    const float stp  = stepv[p];
    const float rlam = 1.0f / lam;
    const bool  lam_big = fabsf(lam) > 1e-6f;

    const unsigned short* bu = Bu + ((size_t)b * LSEQ + c * CLEN) * PDIM + p;
    const float* tb = ts + b * LSEQ + c * CLEN;
    unsigned short* xo = Xbf + ((size_t)b * LSEQ + c * CLEN) * PDIM + p;

    float x = X0[((size_t)b * CCH + c) * PDIM + p];
#pragma unroll 8
    for (int i = 0; i < CLEN; ++i) {
        float t     = tb[i];
        float delta = fmaxf(stp * t, 0.0f);
        float e     = fminf(lam * delta, 20.0f);
        float abar  = __expf(e);
        float gamma = lam_big ? (abar - 1.0f) * rlam : delta;
        x = fmaf(abar, x, gamma * bf2f(bu[(size_t)i * PDIM]));
        xo[(size_t)i * PDIM] = f2bf(x);
    }
}

extern "C" void kernel_launch(void* const* d_in, const int* in_sizes, int n_in,
                              void* d_out, int out_size, void* d_ws, size_t ws_size,
                              hipStream_t stream) {
    (void)in_sizes; (void)n_in; (void)out_size; (void)ws_size;
    const float* u  = (const float*)d_in[0];
    const float* ts = (const float*)d_in[1];
    const float* Lr = (const float*)d_in[2];
    const float* ls = (const float*)d_in[3];
    const float* Bm = (const float*)d_in[4];
    const float* Cm = (const float*)d_in[5];
    const float* Dv = (const float*)d_in[6];
    float* out = (float*)d_out;

    char* ws = (char*)d_ws;
    bf16_t*         u_bf = (bf16_t*)(ws);                          // 32 MB
    bf16_t*         B_bf = (bf16_t*)(ws + (32u << 20));            // 1 MB
    bf16_t*         C_bf = (bf16_t*)(ws + (33u << 20));            // 1 MB
    unsigned short* Bu   = (unsigned short*)(ws + (34u << 20));    // 16 MB (bf16)
    unsigned short* X_bf = (unsigned short*)(ws + (50u << 20));    // 16 MB
    float*          Pagg = (float*)(ws + (66u << 20));             // 1 MB
    float*          Sagg = (float*)(ws + (67u << 20));             // 1 MB
    float*          X0   = (float*)(ws + (68u << 20));             // 1 MB
    float*          stepv= (float*)(ws + (69u << 20));
    float*          lamv = stepv + PDIM;

    // consts + B/C casts fused (1024 blocks x 256)
    setup_kernel<<<1024, 256, 0, stream>>>(Lr, ls, stepv, lamv,
                                           (const float4*)Bm, (ushort4*)B_bf,
                                           (const float4*)Cm, (ushort4*)C_bf);

    cvt_kernel<<<BLM * H_IN / 4 / 256, 256, 0, stream>>>(
        (const float4*)u, (ushort4*)u_bf, BLM * H_IN / 4);

    // GEMM1: Bu[16384,512](bf16) = u_bf[16384,1024] . B_bf[512,1024]^T
    gemm_nt<0, 1><<<dim3(PDIM / 128, BLM / 128), 256, 0, stream>>>(
        u_bf, B_bf, nullptr, Bu, BLM, PDIM, H_IN, nullptr, nullptr);

    // chunked scan -> X (bf16)
    scan_part1<<<dim3(CCH, BSZ), 512, 0, stream>>>(Bu, ts, stepv, lamv, Pagg, Sagg);
    scan_chunk<<<BSZ * PDIM / 256, 256, 0, stream>>>(Pagg, Sagg, X0);
    scan_part3<<<dim3(CCH, BSZ), 512, 0, stream>>>(Bu, ts, stepv, lamv, X0, X_bf);

    // GEMM2: out[16384,1024](fp32) = X_bf[16384,512] . C_bf[1024,512]^T + D*u_bf
    gemm_nt<1, 0><<<dim3(H_OUTD / 128, BLM / 128), 256, 0, stream>>>(
        (const bf16_t*)X_bf, C_bf, out, nullptr, BLM, H_OUTD, PDIM, Dv,
        (const unsigned short*)u_bf);
}

// Round 5
// 196.787 us; speedup vs baseline: 1.5529x; 1.0373x over previous
//
#include <hip/hip_runtime.h>
#include <cstdint>
#include <cstddef>

#define H_IN   1024
#define H_OUTD 1024
#define PDIM   512
#define BSZ    16
#define LSEQ   1024
#define BLM    (BSZ * LSEQ)   // 16384 rows
#define CCH    32             // chunks along L
#define CLEN   32             // steps per chunk (CCH*CLEN == LSEQ)

typedef __bf16 bf16_t;
typedef __bf16 bf16x8 __attribute__((ext_vector_type(8)));
typedef float  floatx4 __attribute__((ext_vector_type(4)));

// exact RNE fp32 -> bf16 bit conversion
__device__ __forceinline__ unsigned short f2bf(float f) {
    unsigned u = __float_as_uint(f);
    u = u + 0x7fffu + ((u >> 16) & 1u);
    return (unsigned short)(u >> 16);
}
__device__ __forceinline__ float bf2f(unsigned short s) {
    return __uint_as_float((unsigned)s << 16);
}

__device__ __forceinline__ void gl_lds16(const void* g, void* l) {
    __builtin_amdgcn_global_load_lds(
        (const __attribute__((address_space(1))) void*)g,
        (__attribute__((address_space(3))) void*)l, 16, 0, 0);
}

// ---------------- fused setup: per-p constants + u/B/C fp32->bf16 casts
// u: 4194304 float4, B: 131072, C: 131072 -> 17408 blocks x 256
#define NU4 (BLM * H_IN / 4)
#define NB4 (PDIM * H_IN / 4)
#define NC4 (H_OUTD * PDIM / 4)
__global__ void setup_kernel(const float* __restrict__ Lraw,
                             const float* __restrict__ lstep,
                             float* __restrict__ stepv,
                             float* __restrict__ lamv,
                             const float4* __restrict__ Usrc,
                             ushort4* __restrict__ Udst,
                             const float4* __restrict__ Bsrc,
                             ushort4* __restrict__ Bdst,
                             const float4* __restrict__ Csrc,
                             ushort4* __restrict__ Cdst) {
    const int gid = blockIdx.x * 256 + threadIdx.x;
    if (gid < PDIM) {
        stepv[gid] = expf(lstep[gid]);  // STEP_RESCALE = 1.0
        float x = Lraw[gid];
        // jax.nn.softplus(x) = max(x,0) + log1p(exp(-|x|))
        float sp = fmaxf(x, 0.0f) + log1pf(expf(-fabsf(x)));
        lamv[gid] = -(sp + 1e-3f);
    }
    if (gid < NU4) {
        float4 v = Usrc[gid];
        ushort4 o;
        o.x = f2bf(v.x); o.y = f2bf(v.y); o.z = f2bf(v.z); o.w = f2bf(v.w);
        Udst[gid] = o;
    } else {
        const int g2 = gid - NU4;
        if (g2 < NB4) {
            float4 v = Bsrc[g2];
            ushort4 o;
            o.x = f2bf(v.x); o.y = f2bf(v.y); o.z = f2bf(v.z); o.w = f2bf(v.w);
            Bdst[g2] = o;
        } else if (g2 < NB4 + NC4) {
            const int g3 = g2 - NB4;
            float4 v = Csrc[g3];
            ushort4 o;
            o.x = f2bf(v.x); o.y = f2bf(v.y); o.z = f2bf(v.z); o.w = f2bf(v.w);
            Cdst[g3] = o;
        }
    }
}

// ---------------- NT bf16 MFMA GEMM: out[m,n] = sum_k A[m,k]*Bm[n,k]
// EPI==1: += Dv[n]*bf2f(U[m,n]).  OUTBF==1: store bf16 to Cb, else fp32 to Cf.
// 128x128 tile, BK=32, 256 threads (4 waves, each 64x64), 16x16x32 MFMA.
// 1D grid, XCD-aware swizzle (GXL = log2 of n-blocks): i = (mh<<(3+GXL))|(n<<3)|r,
// m_blk = (mh<<3)|r, n_blk = n  -> each XCD keeps a 2-4 MB A-footprint in its L2.
template<int EPI, int OUTBF, int GXL>
__global__ __launch_bounds__(256, 4)
void gemm_nt(const bf16_t* __restrict__ A, const bf16_t* __restrict__ Bm,
             float* __restrict__ Cf, unsigned short* __restrict__ Cb,
             int M, int N, int K,
             const float* __restrict__ Dv, const unsigned short* __restrict__ U) {
    __shared__ bf16_t As[128 * 32];
    __shared__ bf16_t Bs[128 * 32];

    const int i     = blockIdx.x;
    const int n_blk = (i >> 3) & ((1 << GXL) - 1);
    const int m_blk = ((i >> (3 + GXL)) << 3) | (i & 7);
    const int m0    = m_blk << 7;
    const int n0    = n_blk << 7;

    const int tid  = threadIdx.x;
    const int lane = tid & 63;
    const int w    = tid >> 6;
    const int wm   = (w & 1) << 6;
    const int wn   = (w >> 1) << 6;
    const int r16  = lane & 15;
    const int q    = lane >> 4;
    const int fsw  = (q ^ (r16 & 3)) << 3;   // XOR-swizzled fragment slot

    // staging: each wave covers 32 rows of each tile via two 16-row chunks
    const int srow = lane >> 2;              // 0..15 within chunk
    const int seg  = (lane & 3) ^ (srow & 3);
    const int c0   = w * 32;
    const int c1   = c0 + 16;

    const bf16_t* gA0 = A  + (size_t)(m0 + c0 + srow) * K + seg * 8;
    const bf16_t* gA1 = A  + (size_t)(m0 + c1 + srow) * K + seg * 8;
    const bf16_t* gB0 = Bm + (size_t)(n0 + c0 + srow) * K + seg * 8;
    const bf16_t* gB1 = Bm + (size_t)(n0 + c1 + srow) * K + seg * 8;
    bf16_t* lA0 = &As[c0 * 32];
    bf16_t* lA1 = &As[c1 * 32];
    bf16_t* lB0 = &Bs[c0 * 32];
    bf16_t* lB1 = &Bs[c1 * 32];

    floatx4 acc[4][4] = {};

    for (int k0 = 0; k0 < K; k0 += 32) {
        gl_lds16(gA0 + k0, lA0);
        gl_lds16(gA1 + k0, lA1);
        gl_lds16(gB0 + k0, lB0);
        gl_lds16(gB1 + k0, lB1);
        __syncthreads();   // drains vmcnt: LDS tiles ready

        bf16x8 af[4], bfr[4];
#pragma unroll
        for (int ii = 0; ii < 4; ++ii) {
            af[ii]  = *(const bf16x8*)&As[(wm + ii * 16 + r16) * 32 + fsw];
            bfr[ii] = *(const bf16x8*)&Bs[(wn + ii * 16 + r16) * 32 + fsw];
        }
#pragma unroll
        for (int mi = 0; mi < 4; ++mi)
#pragma unroll
            for (int ni = 0; ni < 4; ++ni)
                acc[mi][ni] = __builtin_amdgcn_mfma_f32_16x16x32_bf16(
                    af[mi], bfr[ni], acc[mi][ni], 0, 0, 0);
        __syncthreads();   // all waves done reading before next overwrite
    }

    // epilogue: C/D layout row = q*4 + e, col = r16 (verified)
    float dn[4];
    if (EPI == 1) {
#pragma unroll
        for (int ni = 0; ni < 4; ++ni) dn[ni] = Dv[n0 + wn + ni * 16 + r16];
    }
#pragma unroll
    for (int mi = 0; mi < 4; ++mi) {
#pragma unroll
        for (int e = 0; e < 4; ++e) {
            const int m = m0 + wm + mi * 16 + q * 4 + e;
#pragma unroll
            for (int ni = 0; ni < 4; ++ni) {
                const int n = n0 + wn + ni * 16 + r16;
                const size_t idx = (size_t)m * N + n;
                float v = acc[mi][ni][e];
                if (EPI == 1) v += dn[ni] * bf2f(U[idx]);
                if (OUTBF == 1) Cb[idx] = f2bf(v);
                else            Cf[idx] = v;
            }
        }
    }
}

// ---------------- chunked parallel scan, 2 kernels.
// Recurrence (algebraically == reference cumprod/cumsum form):
//   x_l = abar_l * x_{l-1} + gamma_l * bu_l
// Phase 1: per (b, chunk, p): P = prod(abar), S = chunk-local x from 0.
__global__ __launch_bounds__(512)
void scan_part1(const unsigned short* __restrict__ Bu, const float* __restrict__ ts,
                const float* __restrict__ stepv, const float* __restrict__ lamv,
                float* __restrict__ Pagg, float* __restrict__ Sagg) {
    const int c = blockIdx.x;
    const int b = blockIdx.y;
    const int p = threadIdx.x;

    const float lam  = lamv[p];
    const float stp  = stepv[p];
    const float rlam = 1.0f / lam;
    const bool  lam_big = fabsf(lam) > 1e-6f;

    const unsigned short* bu = Bu + ((size_t)b * LSEQ + c * CLEN) * PDIM + p;
    const float* tb = ts + b * LSEQ + c * CLEN;

    float P = 1.0f, S = 0.0f;
#pragma unroll 8
    for (int i = 0; i < CLEN; ++i) {
        float t     = tb[i];
        float delta = fmaxf(stp * t, 0.0f);
        float e     = fminf(lam * delta, 20.0f);
        float abar  = __expf(e);
        float gamma = lam_big ? (abar - 1.0f) * rlam : delta;
        S = fmaf(abar, S, gamma * bf2f(bu[(size_t)i * PDIM]));
        P *= abar;
    }
    const size_t o = ((size_t)b * CCH + c) * PDIM + p;
    Pagg[o] = P;
    Sagg[o] = S;
}

// Phase 2+3 fused: replay aggregate scan (entering state), then walk chunk, emit bf16.
__global__ __launch_bounds__(512)
void scan_part23(const unsigned short* __restrict__ Bu, const float* __restrict__ ts,
                 const float* __restrict__ stepv, const float* __restrict__ lamv,
                 const float* __restrict__ Pagg, const float* __restrict__ Sagg,
                 unsigned short* __restrict__ Xbf) {
    const int c = blockIdx.x;
    const int b = blockIdx.y;
    const int p = threadIdx.x;

    const float lam  = lamv[p];
    const float stp  = stepv[p];
    const float rlam = 1.0f / lam;
    const bool  lam_big = fabsf(lam) > 1e-6f;

    // entering state: scan aggregates of chunks 0..c-1 (uniform trip count per block)
    float x = 0.0f;
    for (int cc = 0; cc < c; ++cc) {
        const size_t o = ((size_t)b * CCH + cc) * PDIM + p;
        x = fmaf(Pagg[o], x, Sagg[o]);
    }

    const unsigned short* bu = Bu + ((size_t)b * LSEQ + c * CLEN) * PDIM + p;
    const float* tb = ts + b * LSEQ + c * CLEN;
    unsigned short* xo = Xbf + ((size_t)b * LSEQ + c * CLEN) * PDIM + p;

#pragma unroll 8
    for (int i = 0; i < CLEN; ++i) {
        float t     = tb[i];
        float delta = fmaxf(stp * t, 0.0f);
        float e     = fminf(lam * delta, 20.0f);
        float abar  = __expf(e);
        float gamma = lam_big ? (abar - 1.0f) * rlam : delta;
        x = fmaf(abar, x, gamma * bf2f(bu[(size_t)i * PDIM]));
        xo[(size_t)i * PDIM] = f2bf(x);
    }
}

extern "C" void kernel_launch(void* const* d_in, const int* in_sizes, int n_in,
                              void* d_out, int out_size, void* d_ws, size_t ws_size,
                              hipStream_t stream) {
    (void)in_sizes; (void)n_in; (void)out_size; (void)ws_size;
    const float* u  = (const float*)d_in[0];
    const float* ts = (const float*)d_in[1];
    const float* Lr = (const float*)d_in[2];
    const float* ls = (const float*)d_in[3];
    const float* Bm = (const float*)d_in[4];
    const float* Cm = (const float*)d_in[5];
    const float* Dv = (const float*)d_in[6];
    float* out = (float*)d_out;

    char* ws = (char*)d_ws;
    bf16_t*         u_bf = (bf16_t*)(ws);                          // 32 MB
    bf16_t*         B_bf = (bf16_t*)(ws + (32u << 20));            // 1 MB
    bf16_t*         C_bf = (bf16_t*)(ws + (33u << 20));            // 1 MB
    unsigned short* Bu   = (unsigned short*)(ws + (34u << 20));    // 16 MB (bf16)
    unsigned short* X_bf = (unsigned short*)(ws + (50u << 20));    // 16 MB
    float*          Pagg = (float*)(ws + (66u << 20));             // 1 MB
    float*          Sagg = (float*)(ws + (67u << 20));             // 1 MB
    float*          stepv= (float*)(ws + (69u << 20));
    float*          lamv = stepv + PDIM;

    // consts + u/B/C casts fused
    setup_kernel<<<(NU4 + NB4 + NC4) / 256, 256, 0, stream>>>(
        Lr, ls, stepv, lamv,
        (const float4*)u,  (ushort4*)u_bf,
        (const float4*)Bm, (ushort4*)B_bf,
        (const float4*)Cm, (ushort4*)C_bf);

    // GEMM1: Bu[16384,512](bf16) = u_bf[16384,1024] . B_bf[512,1024]^T   (GXL=2: 4 n-blocks)
    gemm_nt<0, 1, 2><<<512, 256, 0, stream>>>(
        u_bf, B_bf, nullptr, Bu, BLM, PDIM, H_IN, nullptr, nullptr);

    // chunked scan -> X (bf16)
    scan_part1<<<dim3(CCH, BSZ), 512, 0, stream>>>(Bu, ts, stepv, lamv, Pagg, Sagg);
    scan_part23<<<dim3(CCH, BSZ), 512, 0, stream>>>(Bu, ts, stepv, lamv,
                                                    Pagg, Sagg, X_bf);

    // GEMM2: out[16384,1024](fp32) = X_bf[16384,512] . C_bf[1024,512]^T + D*u_bf  (GXL=3)
    gemm_nt<1, 0, 3><<<1024, 256, 0, stream>>>(
        (const bf16_t*)X_bf, C_bf, out, nullptr, BLM, H_OUTD, PDIM, Dv,
        (const unsigned short*)u_bf);
}